// Round 6
// baseline (4994.801 us; speedup 1.0000x reference)
//
#include <hip/hip_runtime.h>
#include <hip/hip_bf16.h>

#define NLAYERS 6
#define BB 8
#define TT 512
#define DMODEL 2048
#define DSTATE 128
#define DCONV 4
#define DINNER 4096
#define NTOK (BB*TT)              // 4096 tokens
#define NCAT (DINNER + 2*DSTATE)  // 4352 = W_dt rows + W_xp rows

typedef __bf16 bf16x8 __attribute__((ext_vector_type(8)));
typedef float floatx4 __attribute__((ext_vector_type(4)));
typedef unsigned short ushort8v __attribute__((ext_vector_type(8)));
typedef unsigned short ushort4v __attribute__((ext_vector_type(4)));

__device__ __forceinline__ float bf2f(unsigned short u) {
    return __uint_as_float(((unsigned)u) << 16);
}
__device__ __forceinline__ unsigned short f2bf(float f) {
    unsigned u = __float_as_uint(f);
    unsigned r = u + 0x7FFFu + ((u >> 16) & 1u);   // round-nearest-even
    return (unsigned short)(r >> 16);
}
__device__ __forceinline__ float siluf(float x) { return x / (1.f + __expf(-x)); }
__device__ __forceinline__ float softplusf(float x) {
    return fmaxf(x, 0.f) + log1pf(__expf(-fabsf(x)));
}

__device__ __forceinline__ void gload16(const void* g, void* l) {
    __builtin_amdgcn_global_load_lds(
        (const __attribute__((address_space(1))) void*)g,
        (__attribute__((address_space(3))) void*)l, 16, 0, 0);
}

// ---------------- fp32 -> bf16 weight conversion ----------------
__global__ __launch_bounds__(256) void cvt_kernel(const float* __restrict__ s,
                                                  unsigned short* __restrict__ d, int n) {
    int i = (blockIdx.x * blockDim.x + threadIdx.x) * 4;
    if (i < n) {
        float4 v = *(const float4*)(s + i);
        ushort4v o = {f2bf(v.x), f2bf(v.y), f2bf(v.z), f2bf(v.w)};
        *(ushort4v*)(d + i) = o;
    }
}

// ---------------- LayerNorm: fp32 in -> bf16 out ----------------
__global__ __launch_bounds__(256) void ln_kernel(const float* __restrict__ x,
                                                 const float* __restrict__ g,
                                                 const float* __restrict__ b,
                                                 unsigned short* __restrict__ out) {
    const int row = blockIdx.x;
    const float* xr = x + (long)row * DMODEL;
    const int base = threadIdx.x * 8;
    float4 v0 = *(const float4*)(xr + base);
    float4 v1 = *(const float4*)(xr + base + 4);
    float vv[8] = {v0.x, v0.y, v0.z, v0.w, v1.x, v1.y, v1.z, v1.w};
    float s = 0.f, s2 = 0.f;
#pragma unroll
    for (int j = 0; j < 8; j++) { s += vv[j]; s2 += vv[j] * vv[j]; }
#pragma unroll
    for (int off = 32; off >= 1; off >>= 1) {
        s += __shfl_xor(s, off);
        s2 += __shfl_xor(s2, off);
    }
    __shared__ float red[8];
    int wave = threadIdx.x >> 6, lane = threadIdx.x & 63;
    if (lane == 0) { red[wave] = s; red[4 + wave] = s2; }
    __syncthreads();
    s = red[0] + red[1] + red[2] + red[3];
    s2 = red[4] + red[5] + red[6] + red[7];
    float mu = s * (1.f / DMODEL);
    float var = s2 * (1.f / DMODEL) - mu * mu;
    float rs = rsqrtf(var + 1e-5f);
    ushort8v ov;
#pragma unroll
    for (int j = 0; j < 8; j++)
        ov[j] = f2bf((vv[j] - mu) * rs * g[base + j] + b[base + j]);
    *(ushort8v*)&out[(long)row * DMODEL + base] = ov;
}

// ============ (64*MH)x256 MFMA GEMM, register-pipelined frag reads ============
// 512 thr (8 waves: wm M-split, wn N-split), BK=64, double-buffered LDS.
// T2 swizzle: stored 16B chunk = logical ^ (row&7), both sides (0 conflicts, verified).
// Register pipeline: two af-sets + one bfr-set. Per K-tile:
//   issue bfr(k0)+afB(k1); lgkmcnt(MI) -> afA+bfr ready; MFMA(k0) overlaps afB reads
//   issue bfr(k1); lgkmcnt(0)          -> all reads from buf landed (race-safe vs STAGE)
//   BARR; STAGE(t+2 -> buf); vmcnt(MH+4) -> t+1 landed; BARR
//   issue afA(k0 of t+1, from buf^1); MFMA(k1) overlaps those reads
// -> every ds_read burst is covered by an MFMA cluster; LDS port and MFMA pipes overlap.

#define BARR __builtin_amdgcn_s_barrier()
#define SCHB __builtin_amdgcn_sched_barrier(0)
#define PRIO1 __builtin_amdgcn_s_setprio(1)
#define PRIO0 __builtin_amdgcn_s_setprio(0)

template <int EPI, int MH>
__global__ __launch_bounds__(512, 2) void gemm256(const unsigned short* __restrict__ A,
                                                  const unsigned short* __restrict__ B,
                                                  int K, int RY, int RX, int NGX, int ldc,
                                                  unsigned short* __restrict__ Cbf,
                                                  float* __restrict__ Cf,
                                                  const float* __restrict__ resid,
                                                  const float* __restrict__ bias,
                                                  float* __restrict__ dmean,
                                                  float* __restrict__ bcout) {
    constexpr int MI = MH * 2;          // A-frags per wave per k-half
    constexpr int WBAND = MH * 32;      // wave M-band stride in rows
    __shared__ __align__(16) char lds[MH * 16384 + 65536];
    const int tid = threadIdx.x;
    const int w = tid >> 6, lane = tid & 63;
    const int wm = w >> 2, wn = w & 3;
    const int lrow = lane & 15;

    // per-XCD 2D region clustering (block b -> XCD b&7), column-major walk in-region
    const int bidx = blockIdx.x;
    const int xcd = bidx & 7;
    const int l = bidx >> 3;
    const int by = (xcd / NGX) * RY + (l % RY);
    const int bx = (xcd % NGX) * RX + (l / RY);
    const long rowBase = (long)by * (MH * 64);
    const long colBase = (long)bx * 256;

    // T2 read-side: stored chunk = logical ^ (row&7); row&7 == lane&7 for all frags
    const int cb0 = (((lane >> 4))     ^ (lane & 7)) * 16;
    const int cb1 = (((lane >> 4) | 4) ^ (lane & 7)) * 16;
    const char* rdA = lds + wm * (MH / 2) * 8192 + lrow * 128;
    const char* rdB = lds + MH * 16384 + wn * 8192 + lrow * 128;

    // staging: unit = 64 rows x 128B; wave w covers rows w*8..w*8+7 of each unit;
    // lane writes stored slot (lane&7) of row (lane>>3) -> source chunk = slot ^ row
    const int rsub = lane >> 3;
    const int csrc = (lane & 7) ^ (lane >> 3);
    char* ldsw = lds + w * 1024;
    const size_t Kb = (size_t)K;
    const char* pA[MH];
#pragma unroll
    for (int u = 0; u < MH; u++)
        pA[u] = (const char*)(A + (rowBase + u * 64 + w * 8 + rsub) * Kb) + csrc * 16;
    const char* pB[4];
#pragma unroll
    for (int u = 0; u < 4; u++)
        pB[u] = (const char*)(B + (colBase + u * 64 + w * 8 + rsub) * Kb) + csrc * 16;

    floatx4 acc[MI][4];
#pragma unroll
    for (int m = 0; m < MI; m++)
#pragma unroll
        for (int n = 0; n < 4; n++) acc[m][n] = floatx4{0.f, 0.f, 0.f, 0.f};
    bf16x8 afA[MI], afB[MI], bfr[4];

#define RD_AFV(DST, BUF, CK) do { _Pragma("unroll") \
  for (int m_ = 0; m_ < MI; m_++) \
    DST[m_] = *(const bf16x8*)(rdA + (BUF)*(MH*8192) + ((m_>>2)*64 + (m_&3)*16)*128 + (CK)); } while(0)

#define RD_BFV(BUF, CK) do { _Pragma("unroll") \
  for (int n_ = 0; n_ < 4; n_++) \
    bfr[n_] = *(const bf16x8*)(rdB + (BUF)*32768 + n_*2048 + (CK)); } while(0)

// swapped operands: D = B-frag x A-frag -> lane holds 4 consecutive N-cols per acc reg
#define MFMA_SET(AF) do { _Pragma("unroll") \
  for (int mi_ = 0; mi_ < MI; mi_++) { _Pragma("unroll") \
    for (int n_ = 0; n_ < 4; n_++) \
      acc[mi_][n_] = __builtin_amdgcn_mfma_f32_16x16x32_bf16(bfr[n_], AF[mi_], acc[mi_][n_], 0,0,0); } } while(0)

#define STAGE(BUF, OFF) do { \
    _Pragma("unroll") for (int u_ = 0; u_ < MH; u_++) \
        gload16(pA[u_] + (OFF), ldsw + (BUF)*(MH*8192) + u_*8192); \
    _Pragma("unroll") for (int u_ = 0; u_ < 4; u_++) \
        gload16(pB[u_] + (OFF), ldsw + MH*16384 + (BUF)*32768 + u_*8192); } while(0)

#define VMN do { if constexpr (MH == 4) { asm volatile("s_waitcnt vmcnt(8)"); } \
                 else { asm volatile("s_waitcnt vmcnt(6)"); } } while(0)
#define LGKM_MI do { if constexpr (MH == 4) { asm volatile("s_waitcnt lgkmcnt(8)"); } \
                     else { asm volatile("s_waitcnt lgkmcnt(4)"); } SCHB; } while(0)
#define LGKM_0 do { asm volatile("s_waitcnt lgkmcnt(0)"); SCHB; } while(0)

    const int nkt = K >> 6;   // K-tiles (32 or 64)

    // prologue: tiles 0 and 1; drain tile 0, keep tile 1 in flight; preload afA(k0)
    STAGE(0, 0);
    STAGE(1, 128);
    VMN; BARR;
    RD_AFV(afA, 0, cb0);

    for (int t = 0; t < nkt; t++) {
        const int buf = t & 1;
        const size_t off2 = (size_t)((t + 2 < nkt) ? (t + 2) : (nkt - 1)) * 128;
        RD_BFV(buf, cb0);           // bfr(k0)
        RD_AFV(afB, buf, cb1);      // afB(k1), stays in flight past the wait
        LGKM_MI;                    // afA + bfr(k0) landed
        PRIO1; MFMA_SET(afA); PRIO0;        // k0; overlaps afB reads
        RD_BFV(buf, cb1);           // bfr(k1) (WAR on bfr, compiler-ordered)
        LGKM_0;                     // ALL reads from buf landed -> safe to overwrite
        BARR;
        STAGE(buf, off2);           // tile t+2 into freed buf
        VMN;                        // tile t+1 fully landed (t+2 stays in flight)
        BARR;                       // publish buf^1 (tile t+1)
        RD_AFV(afA, buf ^ 1, cb0);  // afA(k0 of t+1); overlapped by MFMA(k1)
        SCHB;
        PRIO1; MFMA_SET(afB); PRIO0;        // k1
    }
#undef RD_AFV
#undef RD_BFV
#undef MFMA_SET
#undef STAGE
#undef VMN
#undef LGKM_MI
#undef LGKM_0

    // ---------------- epilogue (C^T layout: lane&15 = M-row, (lane>>4)*4+reg = N-col) ----------------
    const int cg = (lane >> 4) * 4;
    if constexpr (EPI == 0) {
#pragma unroll
        for (int mi = 0; mi < MI; mi++)
#pragma unroll
            for (int n = 0; n < 4; n++) {
                long row = rowBase + wm * WBAND + mi * 16 + lrow;
                long col = colBase + wn * 64 + n * 16 + cg;
                ushort4v o = {f2bf(acc[mi][n][0]), f2bf(acc[mi][n][1]),
                              f2bf(acc[mi][n][2]), f2bf(acc[mi][n][3])};
                *(ushort4v*)&Cbf[row * ldc + col] = o;
            }
    } else if constexpr (EPI == 2) {
        if (colBase >= DINNER) {
            if (colBase < NCAT) {
                // W_xp region -> bc[NTOK][256], float4 stores (pad column: no stores)
#pragma unroll
                for (int mi = 0; mi < MI; mi++)
#pragma unroll
                    for (int n = 0; n < 4; n++) {
                        long row = rowBase + wm * WBAND + mi * 16 + lrow;
                        long col = colBase - DINNER + wn * 64 + n * 16 + cg;
                        *(floatx4*)&bcout[row * (2 * DSTATE) + col] = acc[mi][n];
                    }
            }
        } else {
            // delta region: softplus(acc + b_dt) summed over cols -> dmean atomics
            float4 bi[4];
#pragma unroll
            for (int n = 0; n < 4; n++)
                bi[n] = *(const float4*)&bias[colBase + wn * 64 + n * 16 + cg];
#pragma unroll
            for (int mi = 0; mi < MI; mi++) {
                float s = 0.f;
#pragma unroll
                for (int n = 0; n < 4; n++) {
                    s += softplusf(acc[mi][n][0] + bi[n].x);
                    s += softplusf(acc[mi][n][1] + bi[n].y);
                    s += softplusf(acc[mi][n][2] + bi[n].z);
                    s += softplusf(acc[mi][n][3] + bi[n].w);
                }
                s += __shfl_xor(s, 16);
                s += __shfl_xor(s, 32);
                if ((lane >> 4) == 0)
                    atomicAdd(&dmean[rowBase + wm * WBAND + mi * 16 + lrow], s);
            }
        }
    } else {  // EPI == 3: fp32 out + residual, float4
#pragma unroll
        for (int mi = 0; mi < MI; mi++)
#pragma unroll
            for (int n = 0; n < 4; n++) {
                long row = rowBase + wm * WBAND + mi * 16 + lrow;
                long col = colBase + wn * 64 + n * 16 + cg;
                floatx4 rv = *(const floatx4*)&resid[row * ldc + col];
                *(floatx4*)&Cf[row * ldc + col] = acc[mi][n] + rv;
            }
    }
}

// ---------------- causal depthwise conv1d + bias + silu ----------------
__global__ __launch_bounds__(256) void conv_silu_kernel(const unsigned short* __restrict__ xr,
                                                        const float* __restrict__ w,
                                                        const float* __restrict__ cb,
                                                        unsigned short* __restrict__ xc) {
    int idx = blockIdx.x * blockDim.x + threadIdx.x;   // NTOK * 512
    int d0 = (idx & 511) * 8;
    int bt = idx >> 9;
    int t = bt & (TT - 1);
    float acc[8];
#pragma unroll
    for (int j = 0; j < 8; j++) acc[j] = cb[d0 + j];
#pragma unroll
    for (int k = 0; k < DCONV; k++) {
        int ts = t - (DCONV - 1) + k;
        if (ts < 0) continue;
        ushort8v v = *(const ushort8v*)&xr[(long)(bt - (DCONV - 1) + k) * (2 * DINNER) + d0];
#pragma unroll
        for (int j = 0; j < 8; j++) acc[j] += bf2f(v[j]) * w[(d0 + j) * DCONV + k];
    }
    ushort8v ov;
#pragma unroll
    for (int j = 0; j < 8; j++) ov[j] = f2bf(siluf(acc[j]));
    *(ushort8v*)&xc[(long)bt * DINNER + d0] = ov;
}

// ---------------- sequential selective-scan (1 wave per batch) ----------------
__global__ void scan_kernel(const float* __restrict__ dmean, const float* __restrict__ bcmat,
                            const float* __restrict__ A_log, float* __restrict__ ys) {
    int b = blockIdx.x, lane = threadIdx.x;   // 64 lanes, 2 states each
    float A0 = -expf(A_log[lane]);
    float A1 = -expf(A_log[lane + 64]);
    float h0 = 0.f, h1 = 0.f;
    const float inv = 1.f / (float)DINNER;
    const float* rowp = bcmat + (long)b * TT * (2 * DSTATE);
    const float* dmp = dmean + b * TT;
    float B0 = rowp[lane], B1 = rowp[64 + lane];
    float C0 = rowp[128 + lane], C1 = rowp[192 + lane];
    float DM = dmp[0];
    for (int t = 0; t < TT; t++) {
        float nB0 = 0.f, nB1 = 0.f, nC0 = 0.f, nC1 = 0.f, nDM = 0.f;
        if (t + 1 < TT) {
            const float* nx = rowp + (long)(t + 1) * 256;
            nB0 = nx[lane]; nB1 = nx[64 + lane];
            nC0 = nx[128 + lane]; nC1 = nx[192 + lane];
            nDM = dmp[t + 1];
        }
        float dm = DM * inv;
        h0 = h0 * __expf(dm * A0) + B0;
        h1 = h1 * __expf(dm * A1) + B1;
        float v = h0 * C0 + h1 * C1;
#pragma unroll
        for (int off = 32; off >= 1; off >>= 1) v += __shfl_xor(v, off);
        if (lane == 0) ys[b * TT + t] = v;
        B0 = nB0; B1 = nB1; C0 = nC0; C1 = nC1; DM = nDM;
    }
}

// ---------------- y = (ys + D_skip*xc) * silu(res) ----------------
__global__ __launch_bounds__(256) void ycomb_kernel(const float* __restrict__ ys,
                                                    const unsigned short* __restrict__ xc,
                                                    const unsigned short* __restrict__ xr,
                                                    const float* __restrict__ dskip,
                                                    unsigned short* __restrict__ yc) {
    int idx = blockIdx.x * blockDim.x + threadIdx.x;
    int d0 = (idx & 511) * 8;
    int bt = idx >> 9;
    float y = ys[bt];
    ushort8v xcv = *(const ushort8v*)&xc[(long)bt * DINNER + d0];
    ushort8v rv = *(const ushort8v*)&xr[(long)bt * (2 * DINNER) + DINNER + d0];
    ushort8v ov;
#pragma unroll
    for (int j = 0; j < 8; j++) {
        float val = (y + dskip[d0 + j] * bf2f(xcv[j])) * siluf(bf2f(rv[j]));
        ov[j] = f2bf(val);
    }
    *(ushort8v*)&yc[(long)bt * DINNER + d0] = ov;
}

extern "C" void kernel_launch(void* const* d_in, const int* in_sizes, int n_in,
                              void* d_out, int out_size, void* d_ws, size_t ws_size,
                              hipStream_t stream) {
    const float* x      = (const float*)d_in[0];
    const float* ln_g   = (const float*)d_in[1];
    const float* ln_b   = (const float*)d_in[2];
    const float* W_in   = (const float*)d_in[3];
    const float* conv_w = (const float*)d_in[4];
    const float* conv_b = (const float*)d_in[5];
    const float* W_xp   = (const float*)d_in[6];
    const float* W_dt   = (const float*)d_in[7];
    const float* b_dt   = (const float*)d_in[8];
    const float* A_log  = (const float*)d_in[9];
    const float* D_skip = (const float*)d_in[10];
    const float* W_out  = (const float*)d_in[11];
    float* out = (float*)d_out;

    // workspace carve
    char* ws = (char*)d_ws;
    const size_t nWin  = (size_t)2 * DINNER * DMODEL;
    const size_t nWdt  = (size_t)DINNER * DINNER;
    const size_t nWxp  = (size_t)2 * DSTATE * DINNER;
    const size_t nWpad = (size_t)256 * DINNER;          // pad rows 4352..4607 for gx=18
    const size_t nWout = (size_t)DMODEL * DINNER;

    unsigned short* wb_in  = (unsigned short*)ws; ws += nWin * 2;
    unsigned short* wb_cat = (unsigned short*)ws; ws += (nWdt + nWxp + nWpad) * 2;
    unsigned short* wb_out = (unsigned short*)ws; ws += nWout * 2;
    unsigned short* xn = (unsigned short*)ws; ws += (size_t)NTOK * DMODEL * 2;
    unsigned short* xr = (unsigned short*)ws; ws += (size_t)NTOK * 2 * DINNER * 2;
    unsigned short* xc = (unsigned short*)ws; ws += (size_t)NTOK * DINNER * 2;
    unsigned short* yc = (unsigned short*)ws; ws += (size_t)NTOK * DINNER * 2;
    float* bc    = (float*)ws; ws += (size_t)NTOK * 2 * DSTATE * 4;
    float* dmean = (float*)ws; ws += (size_t)NTOK * 4;
    float* ysb   = (float*)ws; ws += (size_t)NTOK * 4;
    float* h0    = (float*)ws; ws += (size_t)NTOK * DMODEL * 4;
    float* h1    = (float*)ws; ws += (size_t)NTOK * DMODEL * 4;

    // zero the wb_cat pad once per launch (deterministic; avoids junk NaN reads)
    hipMemsetAsync(wb_cat + nWdt + nWxp, 0, nWpad * 2, stream);

    const float* hin = x;
    for (int l = 0; l < NLAYERS; l++) {
        float* hout = (l == NLAYERS - 1) ? out : ((l & 1) ? h1 : h0);

        cvt_kernel<<<(int)(nWin / 1024), 256, 0, stream>>>(W_in + (size_t)l * nWin, wb_in, (int)nWin);
        cvt_kernel<<<(int)(nWdt / 1024), 256, 0, stream>>>(W_dt + (size_t)l * nWdt, wb_cat, (int)nWdt);
        cvt_kernel<<<(int)(nWxp / 1024), 256, 0, stream>>>(W_xp + (size_t)l * nWxp, wb_cat + nWdt, (int)nWxp);
        cvt_kernel<<<(int)(nWout / 1024), 256, 0, stream>>>(W_out + (size_t)l * nWout, wb_out, (int)nWout);

        hipMemsetAsync(dmean, 0, (size_t)NTOK * 4, stream);

        // 1) LayerNorm
        ln_kernel<<<NTOK, 256, 0, stream>>>(hin, ln_g + l * DMODEL, ln_b + l * DMODEL, xn);

        // 2) x_and_res = xn @ W_in^T  [4096 x 8192], K=2048, BM=256: grid 16y x 32x = 512
        //    regions 8y x 8x per XCD (2x4 region grid)
        gemm256<0, 4><<<512, 512, 0, stream>>>(
            xn, wb_in, DMODEL, 8, 8, 4, 2 * DINNER, xr, nullptr, nullptr, nullptr, nullptr, nullptr);

        // 3) causal depthwise conv + silu
        conv_silu_kernel<<<NTOK * 512 / 256, 256, 0, stream>>>(
            xr, conv_w + (size_t)l * DINNER * DCONV, conv_b + (size_t)l * DINNER, xc);

        // 4) fused [W_dt; W_xp] GEMM: [4096 x 4608(pad)], K=4096, BM=128: grid 32y x 18x = 576
        //    regions 8y x 9x per XCD (4x2 region grid)
        gemm256<2, 2><<<576, 512, 0, stream>>>(
            xc, wb_cat, DINNER, 8, 9, 2, 0, nullptr, nullptr, nullptr,
            b_dt + (size_t)l * DINNER, dmean, bc);

        // 5) sequential scan -> ys
        scan_kernel<<<BB, 64, 0, stream>>>(dmean, bc, A_log + (size_t)l * DSTATE, ysb);

        // 6) y = (ys + D_skip*xc) * silu(res)
        ycomb_kernel<<<NTOK * 512 / 256, 256, 0, stream>>>(
            ysb, xc, xr, D_skip + (size_t)l * DINNER, yc);

        // 7) out = yc @ W_out^T + hin  [4096 x 2048], K=4096, BM=128: grid 32y x 8x = 256
        //    regions 8y x 4x per XCD (4x2 region grid)
        gemm256<3, 2><<<256, 512, 0, stream>>>(
            yc, wb_out, DINNER, 8, 4, 2, DMODEL, nullptr, hout, hin, nullptr, nullptr, nullptr);

        hin = hout;
    }
    (void)in_sizes; (void)n_in; (void)out_size; (void)ws_size;
}

// Round 7
// 4765.966 us; speedup vs baseline: 1.0480x; 1.0480x over previous
//
#include <hip/hip_runtime.h>
#include <hip/hip_bf16.h>

#define NLAYERS 6
#define BB 8
#define TT 512
#define DMODEL 2048
#define DSTATE 128
#define DCONV 4
#define DINNER 4096
#define NTOK (BB*TT)              // 4096 tokens
#define NCAT (DINNER + 2*DSTATE)  // 4352 = W_dt rows + W_xp rows

typedef __bf16 bf16x8 __attribute__((ext_vector_type(8)));
typedef float floatx4 __attribute__((ext_vector_type(4)));
typedef unsigned short ushort8v __attribute__((ext_vector_type(8)));
typedef unsigned short ushort4v __attribute__((ext_vector_type(4)));

__device__ __forceinline__ float bf2f(unsigned short u) {
    return __uint_as_float(((unsigned)u) << 16);
}
__device__ __forceinline__ unsigned short f2bf(float f) {
    unsigned u = __float_as_uint(f);
    unsigned r = u + 0x7FFFu + ((u >> 16) & 1u);   // round-nearest-even
    return (unsigned short)(r >> 16);
}
__device__ __forceinline__ float siluf(float x) { return x / (1.f + __expf(-x)); }
__device__ __forceinline__ float softplusf(float x) {
    return fmaxf(x, 0.f) + log1pf(__expf(-fabsf(x)));
}

__device__ __forceinline__ void gload16(const void* g, void* l) {
    __builtin_amdgcn_global_load_lds(
        (const __attribute__((address_space(1))) void*)g,
        (__attribute__((address_space(3))) void*)l, 16, 0, 0);
}

// ---------------- fp32 -> bf16 weight conversion ----------------
__global__ __launch_bounds__(256) void cvt_kernel(const float* __restrict__ s,
                                                  unsigned short* __restrict__ d, int n) {
    int i = (blockIdx.x * blockDim.x + threadIdx.x) * 4;
    if (i < n) {
        float4 v = *(const float4*)(s + i);
        ushort4v o = {f2bf(v.x), f2bf(v.y), f2bf(v.z), f2bf(v.w)};
        *(ushort4v*)(d + i) = o;
    }
}

// ---------------- LayerNorm: fp32 in -> bf16 out ----------------
__global__ __launch_bounds__(256) void ln_kernel(const float* __restrict__ x,
                                                 const float* __restrict__ g,
                                                 const float* __restrict__ b,
                                                 unsigned short* __restrict__ out) {
    const int row = blockIdx.x;
    const float* xr = x + (long)row * DMODEL;
    const int base = threadIdx.x * 8;
    float4 v0 = *(const float4*)(xr + base);
    float4 v1 = *(const float4*)(xr + base + 4);
    float vv[8] = {v0.x, v0.y, v0.z, v0.w, v1.x, v1.y, v1.z, v1.w};
    float s = 0.f, s2 = 0.f;
#pragma unroll
    for (int j = 0; j < 8; j++) { s += vv[j]; s2 += vv[j] * vv[j]; }
#pragma unroll
    for (int off = 32; off >= 1; off >>= 1) {
        s += __shfl_xor(s, off);
        s2 += __shfl_xor(s2, off);
    }
    __shared__ float red[8];
    int wave = threadIdx.x >> 6, lane = threadIdx.x & 63;
    if (lane == 0) { red[wave] = s; red[4 + wave] = s2; }
    __syncthreads();
    s = red[0] + red[1] + red[2] + red[3];
    s2 = red[4] + red[5] + red[6] + red[7];
    float mu = s * (1.f / DMODEL);
    float var = s2 * (1.f / DMODEL) - mu * mu;
    float rs = rsqrtf(var + 1e-5f);
    ushort8v ov;
#pragma unroll
    for (int j = 0; j < 8; j++)
        ov[j] = f2bf((vv[j] - mu) * rs * g[base + j] + b[base + j]);
    *(ushort8v*)&out[(long)row * DMODEL + base] = ov;
}

// ============ 128x256 MFMA GEMM, 3-buffer LDS, 1 barrier + 1 vmcnt per K-tile ============
// 512 thr (8 waves: wm=w>>2 over M, wn=w&3 over N), BK=64. Wave tile 64x64.
// LDS: 3 buffers x (A 16KB + B 32KB) = 144KB. Buffer for tile t = t%3; staging target
// for t+2 = (t+2)%3 = buffer last read at tile t-1 -> the single tile-start barrier
// (which all waves reach only after finishing tile t-1's reads) makes the overwrite safe.
// Publish: per-wave vmcnt(6) (own tile-t writes landed) + the same barrier (everyone's).
// After the barrier each wave runs its tile INDEPENDENTLY:
//   STAGE(6 gload_lds) ; 16 ds_read_b128 ; lgkm(8) ; MFMA k0 (cb1 reads in flight) ;
//   lgkm(0) ; MFMA k1
// -> waves skew within the tile, so ds_reads of one wave overlap MFMA of its SIMD partner.
// T2 swizzle: stored 16B chunk = logical ^ (row&7), both sides (0 conflicts, verified).

#define BARR __builtin_amdgcn_s_barrier()
#define SCHB __builtin_amdgcn_sched_barrier(0)
#define PRIO1 __builtin_amdgcn_s_setprio(1)
#define PRIO0 __builtin_amdgcn_s_setprio(0)
#define VM6   asm volatile("s_waitcnt vmcnt(6)")
#define LGKM8 do { asm volatile("s_waitcnt lgkmcnt(8)"); SCHB; } while(0)
#define LGKM0 do { asm volatile("s_waitcnt lgkmcnt(0)"); SCHB; } while(0)

#define BUFSZ 49152   // 16KB A + 32KB B

template <int EPI>
__global__ __launch_bounds__(512, 2) void gemm256(const unsigned short* __restrict__ A,
                                                  const unsigned short* __restrict__ B,
                                                  int K, int RY, int ldc,
                                                  unsigned short* __restrict__ Cbf,
                                                  float* __restrict__ Cf,
                                                  const float* __restrict__ resid,
                                                  const float* __restrict__ bias,
                                                  float* __restrict__ dmean,
                                                  float* __restrict__ bcout) {
    __shared__ __align__(16) char lds[3 * BUFSZ];
    const int tid = threadIdx.x;
    const int w = tid >> 6, lane = tid & 63;
    const int wm = w >> 2, wn = w & 3;
    const int lrow = lane & 15;

    // per-XCD clustering: block b -> XCD b&7; each XCD owns RY rows x (all) cols,
    // walked column-major (by fastest) for A-panel reuse in its L2.
    const int xcd = blockIdx.x & 7;
    const int l = blockIdx.x >> 3;
    const int by = xcd * RY + (l % RY);
    const int bx = l / RY;
    const long rowBase = (long)by * 128;
    const long colBase = (long)bx * 256;

    // T2 read-side: stored chunk = logical ^ (row&7); row&7 == lane&7 for all frags
    const int cb0 = (((lane >> 4))     ^ (lane & 7)) * 16;
    const int cb1 = (((lane >> 4) | 4) ^ (lane & 7)) * 16;
    const char* rdA = lds + (wm * 64 + lrow) * 128;
    const char* rdB = lds + 16384 + (wn * 64 + lrow) * 128;

    // staging: unit = 64 rows x 128B (8KB); wave w writes rows w*8..w*8+7 (1KB) of each
    // unit; lane writes stored slot (lane&7) of row (lane>>3) -> source chunk = slot ^ row
    const int rsub = lane >> 3;
    const int csrc = (lane & 7) ^ (lane >> 3);
    char* ldsw = lds + w * 1024;
    const size_t Kb = (size_t)K;
    const char* pA[2];
#pragma unroll
    for (int u = 0; u < 2; u++)
        pA[u] = (const char*)(A + (rowBase + u * 64 + w * 8 + rsub) * Kb) + csrc * 16;
    const char* pB[4];
#pragma unroll
    for (int u = 0; u < 4; u++)
        pB[u] = (const char*)(B + (colBase + u * 64 + w * 8 + rsub) * Kb) + csrc * 16;

    floatx4 acc[4][4];
#pragma unroll
    for (int m = 0; m < 4; m++)
#pragma unroll
        for (int n = 0; n < 4; n++) acc[m][n] = floatx4{0.f, 0.f, 0.f, 0.f};
    bf16x8 af0[4], af1[4], bf0[4], bf1[4];

#define STAGE(BUF, OFF) do { \
    _Pragma("unroll") for (int u_ = 0; u_ < 2; u_++) \
        gload16(pA[u_] + (OFF), ldsw + (BUF)*BUFSZ + u_*8192); \
    _Pragma("unroll") for (int u_ = 0; u_ < 4; u_++) \
        gload16(pB[u_] + (OFF), ldsw + (BUF)*BUFSZ + 16384 + u_*8192); } while(0)

// swapped operands: D = B-frag x A-frag -> lane holds 4 consecutive N-cols per acc reg
#define MFMA16(AF, BF) do { _Pragma("unroll") \
  for (int m_ = 0; m_ < 4; m_++) { _Pragma("unroll") \
    for (int n_ = 0; n_ < 4; n_++) \
      acc[m_][n_] = __builtin_amdgcn_mfma_f32_16x16x32_bf16(BF[n_], AF[m_], acc[m_][n_], 0,0,0); } } while(0)

    const int nkt = K >> 6;   // K-tiles (32 or 64)

    // prologue: stage tiles 0 and 1 (12 loads in flight)
    STAGE(0, 0);
    STAGE(1, 128);

    for (int t = 0; t < nkt; t++) {
        const int buf = t % 3;
        const int bufS = (t + 2) % 3;
        const long bufOff = (long)buf * BUFSZ;
        const size_t off2 = (size_t)((t + 2 < nkt) ? (t + 2) : (nkt - 1)) * 128;
        VM6;                         // my tile-t stage writes landed (t+1's 6 remain)
        BARR;                        // everyone's landed; everyone done reading buf[(t+2)%3]
        STAGE(bufS, off2);           // tile t+2 -> freed buffer
        // 16 ds_read_b128: k0 frags then k1 frags
#pragma unroll
        for (int m_ = 0; m_ < 4; m_++)
            af0[m_] = *(const bf16x8*)(rdA + bufOff + m_ * 2048 + cb0);
#pragma unroll
        for (int n_ = 0; n_ < 4; n_++)
            bf0[n_] = *(const bf16x8*)(rdB + bufOff + n_ * 2048 + cb0);
#pragma unroll
        for (int m_ = 0; m_ < 4; m_++)
            af1[m_] = *(const bf16x8*)(rdA + bufOff + m_ * 2048 + cb1);
#pragma unroll
        for (int n_ = 0; n_ < 4; n_++)
            bf1[n_] = *(const bf16x8*)(rdB + bufOff + n_ * 2048 + cb1);
        LGKM8;                       // k0 frags ready; k1 reads stay in flight
        PRIO1; MFMA16(af0, bf0); PRIO0;
        LGKM0;                       // k1 frags ready
        PRIO1; MFMA16(af1, bf1); PRIO0;
    }
#undef STAGE
#undef MFMA16

    // ---------------- epilogue (C^T layout: lane&15 = M-row, (lane>>4)*4+reg = N-col) ----------------
    const int cg = (lane >> 4) * 4;
    if constexpr (EPI == 0) {
#pragma unroll
        for (int mi = 0; mi < 4; mi++)
#pragma unroll
            for (int n = 0; n < 4; n++) {
                long row = rowBase + wm * 64 + mi * 16 + lrow;
                long col = colBase + wn * 64 + n * 16 + cg;
                ushort4v o = {f2bf(acc[mi][n][0]), f2bf(acc[mi][n][1]),
                              f2bf(acc[mi][n][2]), f2bf(acc[mi][n][3])};
                *(ushort4v*)&Cbf[row * ldc + col] = o;
            }
    } else if constexpr (EPI == 2) {
        if (colBase >= DINNER) {
            // W_xp region -> bc[NTOK][256], float4 stores
#pragma unroll
            for (int mi = 0; mi < 4; mi++)
#pragma unroll
                for (int n = 0; n < 4; n++) {
                    long row = rowBase + wm * 64 + mi * 16 + lrow;
                    long col = colBase - DINNER + wn * 64 + n * 16 + cg;
                    *(floatx4*)&bcout[row * (2 * DSTATE) + col] = acc[mi][n];
                }
        } else {
            // delta region: softplus(acc + b_dt) summed over cols -> dmean atomics
            float4 bi[4];
#pragma unroll
            for (int n = 0; n < 4; n++)
                bi[n] = *(const float4*)&bias[colBase + wn * 64 + n * 16 + cg];
#pragma unroll
            for (int mi = 0; mi < 4; mi++) {
                float s = 0.f;
#pragma unroll
                for (int n = 0; n < 4; n++) {
                    s += softplusf(acc[mi][n][0] + bi[n].x);
                    s += softplusf(acc[mi][n][1] + bi[n].y);
                    s += softplusf(acc[mi][n][2] + bi[n].z);
                    s += softplusf(acc[mi][n][3] + bi[n].w);
                }
                s += __shfl_xor(s, 16);
                s += __shfl_xor(s, 32);
                if ((lane >> 4) == 0)
                    atomicAdd(&dmean[rowBase + wm * 64 + mi * 16 + lrow], s);
            }
        }
    } else {  // EPI == 3: fp32 out + residual, float4
#pragma unroll
        for (int mi = 0; mi < 4; mi++)
#pragma unroll
            for (int n = 0; n < 4; n++) {
                long row = rowBase + wm * 64 + mi * 16 + lrow;
                long col = colBase + wn * 64 + n * 16 + cg;
                floatx4 rv = *(const floatx4*)&resid[row * ldc + col];
                *(floatx4*)&Cf[row * ldc + col] = acc[mi][n] + rv;
            }
    }
}

// ---------------- causal depthwise conv1d + bias + silu ----------------
__global__ __launch_bounds__(256) void conv_silu_kernel(const unsigned short* __restrict__ xr,
                                                        const float* __restrict__ w,
                                                        const float* __restrict__ cb,
                                                        unsigned short* __restrict__ xc) {
    int idx = blockIdx.x * blockDim.x + threadIdx.x;   // NTOK * 512
    int d0 = (idx & 511) * 8;
    int bt = idx >> 9;
    int t = bt & (TT - 1);
    float acc[8];
#pragma unroll
    for (int j = 0; j < 8; j++) acc[j] = cb[d0 + j];
#pragma unroll
    for (int k = 0; k < DCONV; k++) {
        int ts = t - (DCONV - 1) + k;
        if (ts < 0) continue;
        ushort8v v = *(const ushort8v*)&xr[(long)(bt - (DCONV - 1) + k) * (2 * DINNER) + d0];
#pragma unroll
        for (int j = 0; j < 8; j++) acc[j] += bf2f(v[j]) * w[(d0 + j) * DCONV + k];
    }
    ushort8v ov;
#pragma unroll
    for (int j = 0; j < 8; j++) ov[j] = f2bf(siluf(acc[j]));
    *(ushort8v*)&xc[(long)bt * DINNER + d0] = ov;
}

// ---------------- sequential selective-scan (1 wave per batch) ----------------
__global__ void scan_kernel(const float* __restrict__ dmean, const float* __restrict__ bcmat,
                            const float* __restrict__ A_log, float* __restrict__ ys) {
    int b = blockIdx.x, lane = threadIdx.x;   // 64 lanes, 2 states each
    float A0 = -expf(A_log[lane]);
    float A1 = -expf(A_log[lane + 64]);
    float h0 = 0.f, h1 = 0.f;
    const float inv = 1.f / (float)DINNER;
    const float* rowp = bcmat + (long)b * TT * (2 * DSTATE);
    const float* dmp = dmean + b * TT;
    float B0 = rowp[lane], B1 = rowp[64 + lane];
    float C0 = rowp[128 + lane], C1 = rowp[192 + lane];
    float DM = dmp[0];
    for (int t = 0; t < TT; t++) {
        float nB0 = 0.f, nB1 = 0.f, nC0 = 0.f, nC1 = 0.f, nDM = 0.f;
        if (t + 1 < TT) {
            const float* nx = rowp + (long)(t + 1) * 256;
            nB0 = nx[lane]; nB1 = nx[64 + lane];
            nC0 = nx[128 + lane]; nC1 = nx[192 + lane];
            nDM = dmp[t + 1];
        }
        float dm = DM * inv;
        h0 = h0 * __expf(dm * A0) + B0;
        h1 = h1 * __expf(dm * A1) + B1;
        float v = h0 * C0 + h1 * C1;
#pragma unroll
        for (int off = 32; off >= 1; off >>= 1) v += __shfl_xor(v, off);
        if (lane == 0) ys[b * TT + t] = v;
        B0 = nB0; B1 = nB1; C0 = nC0; C1 = nC1; DM = nDM;
    }
}

// ---------------- y = (ys + D_skip*xc) * silu(res) ----------------
__global__ __launch_bounds__(256) void ycomb_kernel(const float* __restrict__ ys,
                                                    const unsigned short* __restrict__ xc,
                                                    const unsigned short* __restrict__ xr,
                                                    const float* __restrict__ dskip,
                                                    unsigned short* __restrict__ yc) {
    int idx = blockIdx.x * blockDim.x + threadIdx.x;
    int d0 = (idx & 511) * 8;
    int bt = idx >> 9;
    float y = ys[bt];
    ushort8v xcv = *(const ushort8v*)&xc[(long)bt * DINNER + d0];
    ushort8v rv = *(const ushort8v*)&xr[(long)bt * (2 * DINNER) + DINNER + d0];
    ushort8v ov;
#pragma unroll
    for (int j = 0; j < 8; j++) {
        float val = (y + dskip[d0 + j] * bf2f(xcv[j])) * siluf(bf2f(rv[j]));
        ov[j] = f2bf(val);
    }
    *(ushort8v*)&yc[(long)bt * DINNER + d0] = ov;
}

extern "C" void kernel_launch(void* const* d_in, const int* in_sizes, int n_in,
                              void* d_out, int out_size, void* d_ws, size_t ws_size,
                              hipStream_t stream) {
    const float* x      = (const float*)d_in[0];
    const float* ln_g   = (const float*)d_in[1];
    const float* ln_b   = (const float*)d_in[2];
    const float* W_in   = (const float*)d_in[3];
    const float* conv_w = (const float*)d_in[4];
    const float* conv_b = (const float*)d_in[5];
    const float* W_xp   = (const float*)d_in[6];
    const float* W_dt   = (const float*)d_in[7];
    const float* b_dt   = (const float*)d_in[8];
    const float* A_log  = (const float*)d_in[9];
    const float* D_skip = (const float*)d_in[10];
    const float* W_out  = (const float*)d_in[11];
    float* out = (float*)d_out;

    // workspace carve
    char* ws = (char*)d_ws;
    const size_t nWin  = (size_t)2 * DINNER * DMODEL;
    const size_t nWdt  = (size_t)DINNER * DINNER;
    const size_t nWxp  = (size_t)2 * DSTATE * DINNER;
    const size_t nWout = (size_t)DMODEL * DINNER;

    unsigned short* wb_in  = (unsigned short*)ws; ws += nWin * 2;
    unsigned short* wb_cat = (unsigned short*)ws; ws += (nWdt + nWxp) * 2;
    unsigned short* wb_out = (unsigned short*)ws; ws += nWout * 2;
    unsigned short* xn = (unsigned short*)ws; ws += (size_t)NTOK * DMODEL * 2;
    unsigned short* xr = (unsigned short*)ws; ws += (size_t)NTOK * 2 * DINNER * 2;
    unsigned short* xc = (unsigned short*)ws; ws += (size_t)NTOK * DINNER * 2;
    unsigned short* yc = (unsigned short*)ws; ws += (size_t)NTOK * DINNER * 2;
    float* bc    = (float*)ws; ws += (size_t)NTOK * 2 * DSTATE * 4;
    float* dmean = (float*)ws; ws += (size_t)NTOK * 4;
    float* ysb   = (float*)ws; ws += (size_t)NTOK * 4;
    float* h0    = (float*)ws; ws += (size_t)NTOK * DMODEL * 4;
    float* h1    = (float*)ws; ws += (size_t)NTOK * DMODEL * 4;

    const float* hin = x;
    for (int l = 0; l < NLAYERS; l++) {
        float* hout = (l == NLAYERS - 1) ? out : ((l & 1) ? h1 : h0);

        cvt_kernel<<<(int)(nWin / 1024), 256, 0, stream>>>(W_in + (size_t)l * nWin, wb_in, (int)nWin);
        cvt_kernel<<<(int)(nWdt / 1024), 256, 0, stream>>>(W_dt + (size_t)l * nWdt, wb_cat, (int)nWdt);
        cvt_kernel<<<(int)(nWxp / 1024), 256, 0, stream>>>(W_xp + (size_t)l * nWxp, wb_cat + nWdt, (int)nWxp);
        cvt_kernel<<<(int)(nWout / 1024), 256, 0, stream>>>(W_out + (size_t)l * nWout, wb_out, (int)nWout);

        hipMemsetAsync(dmean, 0, (size_t)NTOK * 4, stream);

        // 1) LayerNorm
        ln_kernel<<<NTOK, 256, 0, stream>>>(hin, ln_g + l * DMODEL, ln_b + l * DMODEL, xn);

        // 2) x_and_res = xn @ W_in^T  [4096 x 8192], K=2048: grid 32y x 32x = 1024, RY=4
        gemm256<0><<<1024, 512, 0, stream>>>(
            xn, wb_in, DMODEL, 4, 2 * DINNER, xr, nullptr, nullptr, nullptr, nullptr, nullptr);

        // 3) causal depthwise conv + silu
        conv_silu_kernel<<<NTOK * 512 / 256, 256, 0, stream>>>(
            xr, conv_w + (size_t)l * DINNER * DCONV, conv_b + (size_t)l * DINNER, xc);

        // 4) fused [W_dt; W_xp] GEMM: [4096 x 4352], K=4096: grid 32y x 17x = 544, RY=4
        gemm256<2><<<544, 512, 0, stream>>>(
            xc, wb_cat, DINNER, 4, 0, nullptr, nullptr, nullptr,
            b_dt + (size_t)l * DINNER, dmean, bc);

        // 5) sequential scan -> ys
        scan_kernel<<<BB, 64, 0, stream>>>(dmean, bc, A_log + (size_t)l * DSTATE, ysb);

        // 6) y = (ys + D_skip*xc) * silu(res)
        ycomb_kernel<<<NTOK * 512 / 256, 256, 0, stream>>>(
            ysb, xc, xr, D_skip + (size_t)l * DINNER, yc);

        // 7) out = yc @ W_out^T + hin  [4096 x 2048], K=4096: grid 32y x 8x = 256, RY=4
        gemm256<3><<<256, 512, 0, stream>>>(
            yc, wb_out, DINNER, 4, DMODEL, nullptr, hout, hin, nullptr, nullptr, nullptr);

        hin = hout;
    }
    (void)in_sizes; (void)n_in; (void)out_size; (void)ws_size;
}